// Round 13
// baseline (370.946 us; speedup 1.0000x reference)
//
#include <hip/hip_runtime.h>
#include <hip/hip_bf16.h>

#define NB 8
#define NT 256
#define NL 64
#define ND 768

typedef __attribute__((ext_vector_type(4))) float f32x4;
typedef __attribute__((ext_vector_type(8))) short bf16x8;

__device__ __forceinline__ short f2bs(float f) {
    __hip_bfloat16 h = __float2bfloat16(f);
    return *reinterpret_cast<short*>(&h);
}
__device__ __forceinline__ unsigned pack2(float a, float b) {
    return (unsigned)(ushort)f2bs(a) | ((unsigned)(ushort)f2bs(b) << 16);
}

// ---------------- Kernel 1: k/v projections via bf16 MFMA, f32 outputs ------
__global__ __launch_bounds__(256, 4) void projm_kernel(
    const float* __restrict__ E, const float* __restrict__ Wk,
    const float* __restrict__ Wv, float* __restrict__ kws,
    float* __restrict__ vws)
{
    const float* W = (blockIdx.z == 0) ? Wk : Wv;
    float* O       = (blockIdx.z == 0) ? kws : vws;
    const int m0 = blockIdx.x * 64;
    const int e0 = blockIdx.y * 64;

    __shared__ ushort Et[2][4096];
    __shared__ ushort Wt[2][4096];

    const int tid = threadIdx.x;
    const int lane = tid & 63, w = tid >> 6;
    const int fr = lane & 15;
    const int fq = lane >> 4;
    const int row2 = tid >> 4;
    const int c4   = tid & 15;

    const f32x4 z4 = {0.f, 0.f, 0.f, 0.f};
    f32x4 acc[4];
    #pragma unroll
    for (int et = 0; et < 4; ++et) acc[et] = z4;

    float4 ea[2][4], wa[2][4];
    #pragma unroll
    for (int p = 0; p < 4; ++p) {
        ea[0][p] = *(const float4*)(E + (size_t)(m0 + row2 + 16 * p) * ND + c4 * 4);
        wa[0][p] = *(const float4*)(W + (size_t)(e0 + row2 + 16 * p) * ND + c4 * 4);
    }

    #pragma unroll
    for (int dt = 0; dt < 12; ++dt) {
        const int cur = dt & 1, nxt = cur ^ 1;
        #pragma unroll
        for (int p = 0; p < 4; ++p) {
            const int r = row2 + 16 * p;
            const int uidx = (r * 64 + c4 * 4) ^ ((r & 7) << 3);
            uint2 te; te.x = pack2(ea[cur][p].x, ea[cur][p].y); te.y = pack2(ea[cur][p].z, ea[cur][p].w);
            uint2 tw; tw.x = pack2(wa[cur][p].x, wa[cur][p].y); tw.y = pack2(wa[cur][p].z, wa[cur][p].w);
            *(uint2*)&Et[cur][uidx] = te;
            *(uint2*)&Wt[cur][uidx] = tw;
        }
        if (dt < 11) {
            const int c0 = (dt + 1) * 64 + c4 * 4;
            #pragma unroll
            for (int p = 0; p < 4; ++p) {
                ea[nxt][p] = *(const float4*)(E + (size_t)(m0 + row2 + 16 * p) * ND + c0);
                wa[nxt][p] = *(const float4*)(W + (size_t)(e0 + row2 + 16 * p) * ND + c0);
            }
        }
        __syncthreads();
        const int brow = w * 16 + fr;                  // B = E rows (m)
        const int bsw  = (brow & 7) << 3;
        #pragma unroll
        for (int ks = 0; ks < 2; ++ks) {
            bf16x8 bv = *(const bf16x8*)&Et[cur][(brow * 64 + ks * 32 + fq * 8) ^ bsw];
            #pragma unroll
            for (int et = 0; et < 4; ++et) {
                const int arow = et * 16 + fr;         // A = W rows (e)
                bf16x8 af = *(const bf16x8*)&Wt[cur][(arow * 64 + ks * 32 + fq * 8) ^ ((arow & 7) << 3)];
                acc[et] = __builtin_amdgcn_mfma_f32_16x16x32_bf16(af, bv, acc[et], 0, 0, 0);
            }
        }
    }

    float* ob = O + (size_t)(m0 + w * 16 + fr) * ND + e0 + fq * 4;
    #pragma unroll
    for (int et = 0; et < 4; ++et)
        *(f32x4*)(ob + et * 16) = acc[et];
}

// ---------------- Kernel 2a: S = tok @ v^T, 512 threads / 8 waves -----------
// Same dbuf/barrier structure as R12, double the waves: 24 waves/CU.
__global__ __launch_bounds__(512, 6) void s_kernel(
    const int* __restrict__ spk, const float* __restrict__ tok,
    const float* __restrict__ vws, ushort* __restrict__ S_ws, int cap)
{
    __shared__ int mlist[NT];
    __shared__ int wavecnt[8];
    __shared__ ushort At[2][4096];   // tok slab [64 l][64 d] bf16, swizzled
    __shared__ ushort Vt[2][4096];   // v   slab [64 j][64 d] bf16, swizzled
    __shared__ ushort Sb[4096];      // S [64 l][64 j] bf16, swizzled

    const int bt  = blockIdx.x;
    const int b   = bt >> 8;
    const int t   = bt & 255;
    const int tid = threadIdx.x;
    const int lane = tid & 63, w = tid >> 6;

    // ---- Phase 0: same-speaker prefix list (8 waves; tid>255 never match) ----
    const int tgt = spk[b * NT + t];
    int my = -1;
    if (tid <= t) my = spk[b * NT + tid];
    const bool match = (tid <= t) && (my == tgt);
    unsigned long long bal = __ballot(match);
    if (lane == 0) wavecnt[w] = __popcll(bal);
    __syncthreads();
    int off = 0, n = 0;
    #pragma unroll
    for (int ww = 0; ww < 8; ++ww) { if (ww < w) off += wavecnt[ww]; n += wavecnt[ww]; }
    const int before = __popcll(bal & ((1ull << lane) - 1ull));
    if (match) mlist[off + before] = tid;
    __syncthreads();

    const int fr = lane & 15;
    const int fq = lane >> 4;
    const int lt  = w >> 1;          // 0..3: l band (16 rows)
    const int jt0 = (w & 1) * 2;     // 0 or 2: first of 2 j-tiles
    const int row2 = tid >> 4;       // 0..31 staging row base
    const int c4   = tid & 15;       // staging float4 col

    const size_t tokbase = (size_t)bt * NL * ND;
    const float* vbase = vws + (size_t)b * NT * ND;
    const f32x4 z4 = {0.f, 0.f, 0.f, 0.f};

    const int arow = lt * 16 + fr;
    const int asw  = (arow & 7) << 3;

    const int nchunk = min((n + 63) >> 6, cap);
    for (int cc = 0; cc < nchunk; ++cc) {
        const int j0 = cc * 64;
        int gr[2];
        #pragma unroll
        for (int p = 0; p < 2; ++p) {
            const int jj = j0 + row2 + 32 * p;
            gr[p] = mlist[jj < n ? jj : n - 1];
        }
        float4 ta[2][2], va[2][2];
        #pragma unroll
        for (int p = 0; p < 2; ++p) {
            ta[0][p] = *(const float4*)(tok + tokbase + (size_t)(row2 + 32 * p) * ND + c4 * 4);
            va[0][p] = *(const float4*)(vbase + (size_t)gr[p] * ND + c4 * 4);
        }
        f32x4 accS[2] = {z4, z4};

        for (int dt = 0; dt < 12; ++dt) {
            const int cur = dt & 1, nxt = cur ^ 1;
            #pragma unroll
            for (int p = 0; p < 2; ++p) {
                const int r = row2 + 32 * p;
                const int uidx = (r * 64 + c4 * 4) ^ ((r & 7) << 3);
                uint2 tw; tw.x = pack2(ta[cur][p].x, ta[cur][p].y);
                tw.y = pack2(ta[cur][p].z, ta[cur][p].w);
                uint2 vw; vw.x = pack2(va[cur][p].x, va[cur][p].y);
                vw.y = pack2(va[cur][p].z, va[cur][p].w);
                *(uint2*)&At[cur][uidx] = tw;
                *(uint2*)&Vt[cur][uidx] = vw;
            }
            if (dt < 11) {   // prefetch next slab; in flight across barrier+MFMA
                const int c0 = (dt + 1) * 64 + c4 * 4;
                #pragma unroll
                for (int p = 0; p < 2; ++p) {
                    ta[nxt][p] = *(const float4*)(tok + tokbase + (size_t)(row2 + 32 * p) * ND + c0);
                    va[nxt][p] = *(const float4*)(vbase + (size_t)gr[p] * ND + c0);
                }
            }
            __syncthreads();
            #pragma unroll
            for (int ks = 0; ks < 2; ++ks) {
                bf16x8 af = *(const bf16x8*)&At[cur][(arow * 64 + ks * 32 + fq * 8) ^ asw];
                #pragma unroll
                for (int j2 = 0; j2 < 2; ++j2) {
                    const int brow = (jt0 + j2) * 16 + fr;
                    bf16x8 bv = *(const bf16x8*)&Vt[cur][(brow * 64 + ks * 32 + fq * 8) ^ ((brow & 7) << 3)];
                    accS[j2] = __builtin_amdgcn_mfma_f32_16x16x32_bf16(af, bv, accS[j2], 0, 0, 0);
                }
            }
        }

        #pragma unroll
        for (int j2 = 0; j2 < 2; ++j2) {
            #pragma unroll
            for (int i = 0; i < 4; ++i) {
                const int r = lt * 16 + fq * 4 + i;
                const int c = (jt0 + j2) * 16 + fr;
                Sb[(r * 64 + c) ^ ((r & 7) << 3)] = (ushort)f2bs(accS[j2][i]);
            }
        }
        __syncthreads();
        ushort* dst = S_ws + ((size_t)bt * 4 + cc) * 4096;
        {
            const int r = tid >> 3, c8 = tid & 7;
            *(f32x4*)&dst[(size_t)tid * 8] = *(const f32x4*)&Sb[(r * 64 + c8 * 8) ^ ((r & 7) << 3)];
        }
        __syncthreads();
    }
}

// ---------------- Kernel 2b: out = tok + S @ K, swapped operands ------------
__global__ __launch_bounds__(256, 4) void b_kernel(
    const int* __restrict__ spk, const float* __restrict__ tok,
    const float* __restrict__ kws, const ushort* __restrict__ S_ws,
    float* __restrict__ out, int cap)
{
    __shared__ int mlist[NT];
    __shared__ int wavecnt[4];
    __shared__ ushort Sb[4096];    // S bf16 [64 l][64 j], swizzled
    __shared__ ushort kT[8192];    // kT bf16 [128 dc][64 j], swizzled

    const int bt  = blockIdx.x;
    const int st  = blockIdx.y;
    const int b   = bt >> 8;
    const int t   = bt & 255;
    const int tid = threadIdx.x;
    const int lane = tid & 63, w = tid >> 6;
    const int fr = lane & 15;
    const int fq = lane >> 4;

    const size_t tokbase = (size_t)bt * NL * ND;

    // residual float4 loads, issued before everything (independent)
    f32x4 acco[8];
    {
        const float* rbp = tok + tokbase + (size_t)(w * 16 + fr) * ND + st * 128 + fq * 4;
        #pragma unroll
        for (int ct = 0; ct < 8; ++ct)
            acco[ct] = *(const f32x4*)(rbp + ct * 16);
    }

    const int tgt = spk[b * NT + t];
    int my = -1;
    if (tid <= t) my = spk[b * NT + tid];
    const bool match = (tid <= t) && (my == tgt);
    unsigned long long bal = __ballot(match);
    if (lane == 0) wavecnt[w] = __popcll(bal);
    __syncthreads();
    int off = 0;
    #pragma unroll
    for (int ww = 0; ww < 4; ++ww) if (ww < w) off += wavecnt[ww];
    const int n = wavecnt[0] + wavecnt[1] + wavecnt[2] + wavecnt[3];
    const int before = __popcll(bal & ((1ull << lane) - 1ull));
    if (match) mlist[off + before] = tid;
    __syncthreads();

    const int jr = tid >> 2;       // k-row owner (0..63)
    const int q  = tid & 3;        // 4 lanes cover one 64B line
    const float* kbase = kws + (size_t)b * NT * ND;
    const f32x4 zf = {0.f, 0.f, 0.f, 0.f};

    const int nchunk = min((n + 63) >> 6, cap);
    for (int cc = 0; cc < nchunk; ++cc) {
        const int j0 = cc * 64;
        const ushort* src = S_ws + ((size_t)bt * 4 + cc) * 4096;
        f32x4 sv0 = *(const f32x4*)&src[(size_t)tid * 8];
        f32x4 sv1 = *(const f32x4*)&src[(size_t)(256 + tid) * 8];
        const int jj = j0 + jr;
        const int g = (jj < n) ? mlist[jj] : -1;
        f32x4 kreg[8];
        #pragma unroll
        for (int p = 0; p < 8; ++p)
            kreg[p] = (g >= 0)
                ? *(const f32x4*)(kbase + (size_t)g * ND + st * 128 + (q + 4 * p) * 4)
                : zf;

        if (cc > 0) __syncthreads();
        {
            int wsg = tid, r = wsg >> 3, c8 = wsg & 7;
            *(f32x4*)&Sb[(r * 64 + c8 * 8) ^ ((r & 7) << 3)] = sv0;
            wsg = 256 + tid; r = wsg >> 3; c8 = wsg & 7;
            *(f32x4*)&Sb[(r * 64 + c8 * 8) ^ ((r & 7) << 3)] = sv1;
        }
        #pragma unroll
        for (int p = 0; p < 8; ++p) {
            #pragma unroll
            for (int e = 0; e < 4; ++e) {
                const int dc = (q + 4 * p) * 4 + e;
                kT[(dc * 64 + jr) ^ ((dc & 7) << 3)] = (ushort)f2bs(kreg[p][e]);
            }
        }
        __syncthreads();

        const int srow = w * 16 + fr;          // B = S rows (l)
        const int ssw  = (srow & 7) << 3;
        #pragma unroll
        for (int ks = 0; ks < 2; ++ks) {
            bf16x8 bv = *(const bf16x8*)&Sb[(srow * 64 + ks * 32 + fq * 8) ^ ssw];
            #pragma unroll
            for (int ct = 0; ct < 8; ++ct) {
                const int drow = ct * 16 + fr; // A = kT rows (dcol)
                bf16x8 af = *(const bf16x8*)&kT[(drow * 64 + ks * 32 + fq * 8) ^ ((drow & 7) << 3)];
                acco[ct] = __builtin_amdgcn_mfma_f32_16x16x32_bf16(af, bv, acco[ct], 0, 0, 0);
            }
        }
    }

    float* ob = out + tokbase + (size_t)(w * 16 + fr) * ND + st * 128 + fq * 4;
    #pragma unroll
    for (int ct = 0; ct < 8; ++ct)
        *(f32x4*)(ob + ct * 16) = acco[ct];
}

extern "C" void kernel_launch(void* const* d_in, const int* in_sizes, int n_in,
                              void* d_out, int out_size, void* d_ws, size_t ws_size,
                              hipStream_t stream) {
    const int*   spk = (const int*)d_in[1];
    const float* tok = (const float*)d_in[2];
    const float* edu = (const float*)d_in[3];
    const float* Wk  = (const float*)d_in[4];
    const float* Wv  = (const float*)d_in[5];

    const size_t kv_floats = (size_t)NB * NT * ND;
    float* kws = (float*)d_ws;
    float* vws = kws + kv_floats;
    ushort* S_ws = (ushort*)(vws + kv_floats);
    const size_t s_bytes_per_chunkset = (size_t)NB * NT * 4096ull * 2ull;
    size_t avail = (ws_size > 2 * kv_floats * 4) ? (ws_size - 2 * kv_floats * 4) : 0;
    int cap = (int)(avail / s_bytes_per_chunkset);
    if (cap > 4) cap = 4;
    if (cap < 1) cap = 1;
    float* outp = (float*)d_out;

    projm_kernel<<<dim3(2048 / 64, ND / 64, 2), 256, 0, stream>>>(edu, Wk, Wv, kws, vws);
    s_kernel<<<NB * NT, 512, 0, stream>>>(spk, tok, vws, S_ws, cap);
    b_kernel<<<dim3(NB * NT, 6), 256, 0, stream>>>(spk, tok, kws, S_ws, outp, cap);
}

// Round 14
// 352.892 us; speedup vs baseline: 1.0512x; 1.0512x over previous
//
#include <hip/hip_runtime.h>
#include <hip/hip_bf16.h>

#define NB 8
#define NT 256
#define NL 64
#define ND 768

typedef __attribute__((ext_vector_type(4))) float f32x4;
typedef __attribute__((ext_vector_type(8))) short bf16x8;

__device__ __forceinline__ short f2bs(float f) {
    __hip_bfloat16 h = __float2bfloat16(f);
    return *reinterpret_cast<short*>(&h);
}
__device__ __forceinline__ unsigned pack2(float a, float b) {
    return (unsigned)(ushort)f2bs(a) | ((unsigned)(ushort)f2bs(b) << 16);
}

// ---------------- Kernel 1: k/v projections via bf16 MFMA, f32 outputs ------
__global__ __launch_bounds__(256, 4) void projm_kernel(
    const float* __restrict__ E, const float* __restrict__ Wk,
    const float* __restrict__ Wv, float* __restrict__ kws,
    float* __restrict__ vws)
{
    const float* W = (blockIdx.z == 0) ? Wk : Wv;
    float* O       = (blockIdx.z == 0) ? kws : vws;
    const int m0 = blockIdx.x * 64;
    const int e0 = blockIdx.y * 64;

    __shared__ ushort Et[2][4096];
    __shared__ ushort Wt[2][4096];

    const int tid = threadIdx.x;
    const int lane = tid & 63, w = tid >> 6;
    const int fr = lane & 15;
    const int fq = lane >> 4;
    const int row2 = tid >> 4;
    const int c4   = tid & 15;

    const f32x4 z4 = {0.f, 0.f, 0.f, 0.f};
    f32x4 acc[4];
    #pragma unroll
    for (int et = 0; et < 4; ++et) acc[et] = z4;

    float4 ea[2][4], wa[2][4];
    #pragma unroll
    for (int p = 0; p < 4; ++p) {
        ea[0][p] = *(const float4*)(E + (size_t)(m0 + row2 + 16 * p) * ND + c4 * 4);
        wa[0][p] = *(const float4*)(W + (size_t)(e0 + row2 + 16 * p) * ND + c4 * 4);
    }

    #pragma unroll
    for (int dt = 0; dt < 12; ++dt) {
        const int cur = dt & 1, nxt = cur ^ 1;
        #pragma unroll
        for (int p = 0; p < 4; ++p) {
            const int r = row2 + 16 * p;
            const int uidx = (r * 64 + c4 * 4) ^ ((r & 7) << 3);
            uint2 te; te.x = pack2(ea[cur][p].x, ea[cur][p].y); te.y = pack2(ea[cur][p].z, ea[cur][p].w);
            uint2 tw; tw.x = pack2(wa[cur][p].x, wa[cur][p].y); tw.y = pack2(wa[cur][p].z, wa[cur][p].w);
            *(uint2*)&Et[cur][uidx] = te;
            *(uint2*)&Wt[cur][uidx] = tw;
        }
        if (dt < 11) {
            const int c0 = (dt + 1) * 64 + c4 * 4;
            #pragma unroll
            for (int p = 0; p < 4; ++p) {
                ea[nxt][p] = *(const float4*)(E + (size_t)(m0 + row2 + 16 * p) * ND + c0);
                wa[nxt][p] = *(const float4*)(W + (size_t)(e0 + row2 + 16 * p) * ND + c0);
            }
        }
        __syncthreads();
        const int brow = w * 16 + fr;                  // B = E rows (m)
        const int bsw  = (brow & 7) << 3;
        #pragma unroll
        for (int ks = 0; ks < 2; ++ks) {
            bf16x8 bv = *(const bf16x8*)&Et[cur][(brow * 64 + ks * 32 + fq * 8) ^ bsw];
            #pragma unroll
            for (int et = 0; et < 4; ++et) {
                const int arow = et * 16 + fr;         // A = W rows (e)
                bf16x8 af = *(const bf16x8*)&Wt[cur][(arow * 64 + ks * 32 + fq * 8) ^ ((arow & 7) << 3)];
                acc[et] = __builtin_amdgcn_mfma_f32_16x16x32_bf16(af, bv, acc[et], 0, 0, 0);
            }
        }
    }

    float* ob = O + (size_t)(m0 + w * 16 + fr) * ND + e0 + fq * 4;
    #pragma unroll
    for (int et = 0; et < 4; ++et)
        *(f32x4*)(ob + et * 16) = acc[et];
}

// ---------------- Kernel 2a: S = tok @ v^T (R12 + j-tile skipping) ----------
__global__ __launch_bounds__(256, 3) void s_kernel(
    const int* __restrict__ spk, const float* __restrict__ tok,
    const float* __restrict__ vws, ushort* __restrict__ S_ws, int cap)
{
    __shared__ int mlist[NT];
    __shared__ int wavecnt[4];
    __shared__ ushort At[2][4096];   // tok slab [64 l][64 d] bf16, swizzled
    __shared__ ushort Vt[2][4096];   // v   slab [64 j][64 d] bf16, swizzled
    __shared__ ushort Sb[4096];      // S [64 l][64 j] bf16, swizzled

    const int bt  = blockIdx.x;
    const int b   = bt >> 8;
    const int t   = bt & 255;
    const int tid = threadIdx.x;

    const int tgt = spk[b * NT + t];
    int my = -1;
    if (tid <= t) my = spk[b * NT + tid];
    const bool match = (tid <= t) && (my == tgt);
    unsigned long long bal = __ballot(match);
    const int lane = tid & 63, w = tid >> 6;
    if (lane == 0) wavecnt[w] = __popcll(bal);
    __syncthreads();
    int off = 0;
    #pragma unroll
    for (int ww = 0; ww < 4; ++ww) if (ww < w) off += wavecnt[ww];
    const int n = wavecnt[0] + wavecnt[1] + wavecnt[2] + wavecnt[3];
    const int before = __popcll(bal & ((1ull << lane) - 1ull));
    if (match) mlist[off + before] = tid;
    __syncthreads();

    const int fr = lane & 15;
    const int fq = lane >> 4;
    const int rb = tid >> 4;       // staging row base (0..15)
    const int c4 = tid & 15;       // staging float4 col

    const size_t tokbase = (size_t)bt * NL * ND;
    const float* vbase = vws + (size_t)b * NT * ND;
    const f32x4 z4 = {0.f, 0.f, 0.f, 0.f};

    const int nchunk = min((n + 63) >> 6, cap);
    for (int cc = 0; cc < nchunk; ++cc) {
        const int j0 = cc * 64;
        const int m = min(64, n - j0);
        const int njt = (m + 15) >> 4;      // active j-tiles: 1..4
        int gr[4];
        #pragma unroll
        for (int p = 0; p < 4; ++p) {
            const int jj = j0 + rb + 16 * p;
            gr[p] = mlist[jj < n ? jj : n - 1];
        }
        float4 ta[4], va[4];
        #pragma unroll
        for (int p = 0; p < 4; ++p) {
            ta[p] = *(const float4*)(tok + tokbase + (size_t)(rb + 16 * p) * ND + c4 * 4);
            if (p < njt)
                va[p] = *(const float4*)(vbase + (size_t)gr[p] * ND + c4 * 4);
        }
        f32x4 accS[4];
        #pragma unroll
        for (int jt = 0; jt < 4; ++jt) accS[jt] = z4;

        for (int dt = 0; dt < 12; ++dt) {
            const int cur = dt & 1;
            #pragma unroll
            for (int p = 0; p < 4; ++p) {
                const int row = rb + 16 * p;
                const int uidx = (row * 64 + c4 * 4) ^ ((row & 7) << 3);
                uint2 tw; tw.x = pack2(ta[p].x, ta[p].y); tw.y = pack2(ta[p].z, ta[p].w);
                *(uint2*)&At[cur][uidx] = tw;
                if (p < njt) {
                    uint2 vw; vw.x = pack2(va[p].x, va[p].y); vw.y = pack2(va[p].z, va[p].w);
                    *(uint2*)&Vt[cur][uidx] = vw;
                }
            }
            if (dt < 11) {
                const int c0 = (dt + 1) * 64 + c4 * 4;
                #pragma unroll
                for (int p = 0; p < 4; ++p) {
                    ta[p] = *(const float4*)(tok + tokbase + (size_t)(rb + 16 * p) * ND + c0);
                    if (p < njt)
                        va[p] = *(const float4*)(vbase + (size_t)gr[p] * ND + c0);
                }
            }
            __syncthreads();
            const int arow = w * 16 + fr;
            #pragma unroll
            for (int ks = 0; ks < 2; ++ks) {
                bf16x8 af = *(const bf16x8*)&At[cur][(arow * 64 + ks * 32 + fq * 8) ^ ((arow & 7) << 3)];
                #pragma unroll
                for (int jt = 0; jt < 4; ++jt) {
                    if (jt < njt) {
                        const int brow = jt * 16 + fr;
                        bf16x8 bv = *(const bf16x8*)&Vt[cur][(brow * 64 + ks * 32 + fq * 8) ^ ((brow & 7) << 3)];
                        accS[jt] = __builtin_amdgcn_mfma_f32_16x16x32_bf16(af, bv, accS[jt], 0, 0, 0);
                    }
                }
            }
        }

        // accS[jt>=njt] is zero -> padded S columns are clean zeros
        #pragma unroll
        for (int jt = 0; jt < 4; ++jt) {
            #pragma unroll
            for (int i = 0; i < 4; ++i) {
                const int r = w * 16 + fq * 4 + i;
                const int c = jt * 16 + fr;
                Sb[(r * 64 + c) ^ ((r & 7) << 3)] = (ushort)f2bs(accS[jt][i]);
            }
        }
        __syncthreads();
        ushort* dst = S_ws + ((size_t)bt * 4 + cc) * 4096;
        #pragma unroll
        for (int g = 0; g < 2; ++g) {
            const int wsg = g * 256 + tid;
            const int r = wsg >> 3, c8 = wsg & 7;
            *(f32x4*)&dst[(size_t)wsg * 8] = *(const f32x4*)&Sb[(r * 64 + c8 * 8) ^ ((r & 7) << 3)];
        }
        __syncthreads();
    }
}

// ---------------- Kernel 2b: out = tok + S @ K (R12 + K-half skipping) ------
__global__ __launch_bounds__(256, 4) void b_kernel(
    const int* __restrict__ spk, const float* __restrict__ tok,
    const float* __restrict__ kws, const ushort* __restrict__ S_ws,
    float* __restrict__ out, int cap)
{
    __shared__ int mlist[NT];
    __shared__ int wavecnt[4];
    __shared__ ushort Sb[4096];    // S bf16 [64 l][64 j], swizzled
    __shared__ ushort kT[8192];    // kT bf16 [128 dc][64 j], swizzled

    const int bt  = blockIdx.x;
    const int st  = blockIdx.y;
    const int b   = bt >> 8;
    const int t   = bt & 255;
    const int tid = threadIdx.x;
    const int lane = tid & 63, w = tid >> 6;
    const int fr = lane & 15;
    const int fq = lane >> 4;

    const size_t tokbase = (size_t)bt * NL * ND;

    // residual float4 loads, issued before everything (independent)
    f32x4 acco[8];
    {
        const float* rbp = tok + tokbase + (size_t)(w * 16 + fr) * ND + st * 128 + fq * 4;
        #pragma unroll
        for (int ct = 0; ct < 8; ++ct)
            acco[ct] = *(const f32x4*)(rbp + ct * 16);
    }

    const int tgt = spk[b * NT + t];
    int my = -1;
    if (tid <= t) my = spk[b * NT + tid];
    const bool match = (tid <= t) && (my == tgt);
    unsigned long long bal = __ballot(match);
    if (lane == 0) wavecnt[w] = __popcll(bal);
    __syncthreads();
    int off = 0;
    #pragma unroll
    for (int ww = 0; ww < 4; ++ww) if (ww < w) off += wavecnt[ww];
    const int n = wavecnt[0] + wavecnt[1] + wavecnt[2] + wavecnt[3];
    const int before = __popcll(bal & ((1ull << lane) - 1ull));
    if (match) mlist[off + before] = tid;
    __syncthreads();

    const int jr = tid >> 2;       // k-row owner (0..63)
    const int q  = tid & 3;        // 4 lanes cover one 64B line
    const float* kbase = kws + (size_t)b * NT * ND;
    const f32x4 zf = {0.f, 0.f, 0.f, 0.f};

    const int nchunk = min((n + 63) >> 6, cap);
    for (int cc = 0; cc < nchunk; ++cc) {
        const int j0 = cc * 64;
        const int m = min(64, n - j0);
        const int nks = (m + 31) >> 5;      // active K-halves: 1..2
        const bool act = (jr < nks * 32);   // this thread's kT row is consumed
        const ushort* src = S_ws + ((size_t)bt * 4 + cc) * 4096;
        f32x4 sv0 = *(const f32x4*)&src[(size_t)tid * 8];
        f32x4 sv1 = *(const f32x4*)&src[(size_t)(256 + tid) * 8];
        const int jj = j0 + jr;
        const int g = (jj < n) ? mlist[jj] : -1;
        f32x4 kreg[8];
        if (act) {
            #pragma unroll
            for (int p = 0; p < 8; ++p)
                kreg[p] = (g >= 0)
                    ? *(const f32x4*)(kbase + (size_t)g * ND + st * 128 + (q + 4 * p) * 4)
                    : zf;
        }

        if (cc > 0) __syncthreads();
        {
            int wsg = tid, r = wsg >> 3, c8 = wsg & 7;
            *(f32x4*)&Sb[(r * 64 + c8 * 8) ^ ((r & 7) << 3)] = sv0;
            wsg = 256 + tid; r = wsg >> 3; c8 = wsg & 7;
            *(f32x4*)&Sb[(r * 64 + c8 * 8) ^ ((r & 7) << 3)] = sv1;
        }
        if (act) {
            #pragma unroll
            for (int p = 0; p < 8; ++p) {
                #pragma unroll
                for (int e = 0; e < 4; ++e) {
                    const int dc = (q + 4 * p) * 4 + e;
                    kT[(dc * 64 + jr) ^ ((dc & 7) << 3)] = (ushort)f2bs(kreg[p][e]);
                }
            }
        }
        __syncthreads();

        const int srow = w * 16 + fr;          // B = S rows (l)
        const int ssw  = (srow & 7) << 3;
        #pragma unroll
        for (int ks = 0; ks < 2; ++ks) {
            if (ks < nks) {
                bf16x8 bv = *(const bf16x8*)&Sb[(srow * 64 + ks * 32 + fq * 8) ^ ssw];
                #pragma unroll
                for (int ct = 0; ct < 8; ++ct) {
                    const int drow = ct * 16 + fr; // A = kT rows (dcol)
                    bf16x8 af = *(const bf16x8*)&kT[(drow * 64 + ks * 32 + fq * 8) ^ ((drow & 7) << 3)];
                    acco[ct] = __builtin_amdgcn_mfma_f32_16x16x32_bf16(af, bv, acco[ct], 0, 0, 0);
                }
            }
        }
    }

    float* ob = out + tokbase + (size_t)(w * 16 + fr) * ND + st * 128 + fq * 4;
    #pragma unroll
    for (int ct = 0; ct < 8; ++ct)
        *(f32x4*)(ob + ct * 16) = acco[ct];
}

extern "C" void kernel_launch(void* const* d_in, const int* in_sizes, int n_in,
                              void* d_out, int out_size, void* d_ws, size_t ws_size,
                              hipStream_t stream) {
    const int*   spk = (const int*)d_in[1];
    const float* tok = (const float*)d_in[2];
    const float* edu = (const float*)d_in[3];
    const float* Wk  = (const float*)d_in[4];
    const float* Wv  = (const float*)d_in[5];

    const size_t kv_floats = (size_t)NB * NT * ND;
    float* kws = (float*)d_ws;
    float* vws = kws + kv_floats;
    ushort* S_ws = (ushort*)(vws + kv_floats);
    const size_t s_bytes_per_chunkset = (size_t)NB * NT * 4096ull * 2ull;
    size_t avail = (ws_size > 2 * kv_floats * 4) ? (ws_size - 2 * kv_floats * 4) : 0;
    int cap = (int)(avail / s_bytes_per_chunkset);
    if (cap > 4) cap = 4;
    if (cap < 1) cap = 1;
    float* outp = (float*)d_out;

    projm_kernel<<<dim3(2048 / 64, ND / 64, 2), 256, 0, stream>>>(edu, Wk, Wv, kws, vws);
    s_kernel<<<NB * NT, 256, 0, stream>>>(spk, tok, vws, S_ws, cap);
    b_kernel<<<dim3(NB * NT, 6), 256, 0, stream>>>(spk, tok, kws, S_ws, outp, cap);
}

// Round 15
// 315.825 us; speedup vs baseline: 1.1745x; 1.1174x over previous
//
#include <hip/hip_runtime.h>
#include <hip/hip_bf16.h>

#define NB 8
#define NT 256
#define NL 64
#define ND 768

typedef __attribute__((ext_vector_type(4))) float f32x4;
typedef __attribute__((ext_vector_type(8))) short bf16x8;

__device__ __forceinline__ short f2bs(float f) {
    __hip_bfloat16 h = __float2bfloat16(f);
    return *reinterpret_cast<short*>(&h);
}
__device__ __forceinline__ unsigned pack2(float a, float b) {
    return (unsigned)(ushort)f2bs(a) | ((unsigned)(ushort)f2bs(b) << 16);
}

// ---------------- Kernel 1: k/v projections via bf16 MFMA, f32 outputs ------
__global__ __launch_bounds__(256, 4) void projm_kernel(
    const float* __restrict__ E, const float* __restrict__ Wk,
    const float* __restrict__ Wv, float* __restrict__ kws,
    float* __restrict__ vws)
{
    const float* W = (blockIdx.z == 0) ? Wk : Wv;
    float* O       = (blockIdx.z == 0) ? kws : vws;
    const int m0 = blockIdx.x * 64;
    const int e0 = blockIdx.y * 64;

    __shared__ ushort Et[2][4096];
    __shared__ ushort Wt[2][4096];

    const int tid = threadIdx.x;
    const int lane = tid & 63, w = tid >> 6;
    const int fr = lane & 15;
    const int fq = lane >> 4;
    const int row2 = tid >> 4;
    const int c4   = tid & 15;

    const f32x4 z4 = {0.f, 0.f, 0.f, 0.f};
    f32x4 acc[4];
    #pragma unroll
    for (int et = 0; et < 4; ++et) acc[et] = z4;

    float4 ea[2][4], wa[2][4];
    #pragma unroll
    for (int p = 0; p < 4; ++p) {
        ea[0][p] = *(const float4*)(E + (size_t)(m0 + row2 + 16 * p) * ND + c4 * 4);
        wa[0][p] = *(const float4*)(W + (size_t)(e0 + row2 + 16 * p) * ND + c4 * 4);
    }

    #pragma unroll
    for (int dt = 0; dt < 12; ++dt) {
        const int cur = dt & 1, nxt = cur ^ 1;
        #pragma unroll
        for (int p = 0; p < 4; ++p) {
            const int r = row2 + 16 * p;
            const int uidx = (r * 64 + c4 * 4) ^ ((r & 7) << 3);
            uint2 te; te.x = pack2(ea[cur][p].x, ea[cur][p].y); te.y = pack2(ea[cur][p].z, ea[cur][p].w);
            uint2 tw; tw.x = pack2(wa[cur][p].x, wa[cur][p].y); tw.y = pack2(wa[cur][p].z, wa[cur][p].w);
            *(uint2*)&Et[cur][uidx] = te;
            *(uint2*)&Wt[cur][uidx] = tw;
        }
        if (dt < 11) {
            const int c0 = (dt + 1) * 64 + c4 * 4;
            #pragma unroll
            for (int p = 0; p < 4; ++p) {
                ea[nxt][p] = *(const float4*)(E + (size_t)(m0 + row2 + 16 * p) * ND + c0);
                wa[nxt][p] = *(const float4*)(W + (size_t)(e0 + row2 + 16 * p) * ND + c0);
            }
        }
        __syncthreads();
        const int brow = w * 16 + fr;                  // B = E rows (m)
        const int bsw  = (brow & 7) << 3;
        #pragma unroll
        for (int ks = 0; ks < 2; ++ks) {
            bf16x8 bv = *(const bf16x8*)&Et[cur][(brow * 64 + ks * 32 + fq * 8) ^ bsw];
            #pragma unroll
            for (int et = 0; et < 4; ++et) {
                const int arow = et * 16 + fr;         // A = W rows (e)
                bf16x8 af = *(const bf16x8*)&Wt[cur][(arow * 64 + ks * 32 + fq * 8) ^ ((arow & 7) << 3)];
                acc[et] = __builtin_amdgcn_mfma_f32_16x16x32_bf16(af, bv, acc[et], 0, 0, 0);
            }
        }
    }

    float* ob = O + (size_t)(m0 + w * 16 + fr) * ND + e0 + fq * 4;
    #pragma unroll
    for (int et = 0; et < 4; ++et)
        *(f32x4*)(ob + et * 16) = acc[et];
}

// ---------------- Kernel 2: fused S + out per (b,t) -------------------------
// Phase 1 = R12 s_kernel body (At/Vt dbuf, S -> Sb in LDS).
// Phase 2 = R12 b_kernel body (kT aliases At union; residual re-read is L2-hot).
__global__ __launch_bounds__(256, 3) void fused_kernel(
    const int* __restrict__ spk, const float* __restrict__ tok,
    const float* __restrict__ kws, const float* __restrict__ vws,
    float* __restrict__ out)
{
    __shared__ int mlist[NT];
    __shared__ int wavecnt[4];
    __shared__ ushort U[8192];       // phase1: At[2][4096] | phase2: kT[8192]
    __shared__ ushort Vt[2][4096];   // v slab dbuf
    __shared__ ushort Sb[4096];      // S bf16 [64 l][64 j], swizzled

    ushort* At0 = U;
    ushort* At1 = U + 4096;
    ushort* kT  = U;

    const int bt  = blockIdx.x;
    const int b   = bt >> 8;
    const int t   = bt & 255;
    const int tid = threadIdx.x;

    // ---- Phase 0: same-speaker prefix list ----
    const int tgt = spk[b * NT + t];
    int my = -1;
    if (tid <= t) my = spk[b * NT + tid];
    const bool match = (tid <= t) && (my == tgt);
    unsigned long long bal = __ballot(match);
    const int lane = tid & 63, w = tid >> 6;
    if (lane == 0) wavecnt[w] = __popcll(bal);
    __syncthreads();
    int off = 0;
    #pragma unroll
    for (int ww = 0; ww < 4; ++ww) if (ww < w) off += wavecnt[ww];
    const int n = wavecnt[0] + wavecnt[1] + wavecnt[2] + wavecnt[3];
    const int before = __popcll(bal & ((1ull << lane) - 1ull));
    if (match) mlist[off + before] = tid;
    __syncthreads();

    const int fr = lane & 15;
    const int fq = lane >> 4;
    const int rb = tid >> 4;       // phase1 staging row base (0..15)
    const int c4 = tid & 15;       // phase1 staging float4 col
    const int jr = tid >> 2;       // phase2 k-row owner (0..63)
    const int q  = tid & 3;        // phase2: 4 lanes cover one 64B line

    const size_t tokbase = (size_t)bt * NL * ND;
    const float* vbase = vws + (size_t)b * NT * ND;
    const float* kbase = kws + (size_t)b * NT * ND;
    const f32x4 z4 = {0.f, 0.f, 0.f, 0.f};

    const int nchunk = min((n + 63) >> 6, 4);
    for (int cc = 0; cc < nchunk; ++cc) {
        const int j0 = cc * 64;

        // ================= Phase 1: S = tok @ v^T =================
        int gr[4];
        #pragma unroll
        for (int p = 0; p < 4; ++p) {
            const int jj = j0 + rb + 16 * p;
            gr[p] = mlist[jj < n ? jj : n - 1];
        }
        float4 ta[4], va[4];
        #pragma unroll
        for (int p = 0; p < 4; ++p) {
            ta[p] = *(const float4*)(tok + tokbase + (size_t)(rb + 16 * p) * ND + c4 * 4);
            va[p] = *(const float4*)(vbase + (size_t)gr[p] * ND + c4 * 4);
        }
        f32x4 accS[4];
        #pragma unroll
        for (int jt = 0; jt < 4; ++jt) accS[jt] = z4;

        for (int dt = 0; dt < 12; ++dt) {
            const int cur = dt & 1;
            ushort* Atc = cur ? At1 : At0;
            #pragma unroll
            for (int p = 0; p < 4; ++p) {
                const int row = rb + 16 * p;
                const int uidx = (row * 64 + c4 * 4) ^ ((row & 7) << 3);
                uint2 tw; tw.x = pack2(ta[p].x, ta[p].y); tw.y = pack2(ta[p].z, ta[p].w);
                uint2 vw; vw.x = pack2(va[p].x, va[p].y); vw.y = pack2(va[p].z, va[p].w);
                *(uint2*)&Atc[uidx] = tw;
                *(uint2*)&Vt[cur][uidx] = vw;
            }
            if (dt < 11) {
                const int c0 = (dt + 1) * 64 + c4 * 4;
                #pragma unroll
                for (int p = 0; p < 4; ++p) {
                    ta[p] = *(const float4*)(tok + tokbase + (size_t)(rb + 16 * p) * ND + c0);
                    va[p] = *(const float4*)(vbase + (size_t)gr[p] * ND + c0);
                }
            }
            __syncthreads();
            const int arow = w * 16 + fr;
            #pragma unroll
            for (int ks = 0; ks < 2; ++ks) {
                bf16x8 af = *(const bf16x8*)&Atc[(arow * 64 + ks * 32 + fq * 8) ^ ((arow & 7) << 3)];
                #pragma unroll
                for (int jt = 0; jt < 4; ++jt) {
                    const int brow = jt * 16 + fr;
                    bf16x8 bv = *(const bf16x8*)&Vt[cur][(brow * 64 + ks * 32 + fq * 8) ^ ((brow & 7) << 3)];
                    accS[jt] = __builtin_amdgcn_mfma_f32_16x16x32_bf16(af, bv, accS[jt], 0, 0, 0);
                }
            }
        }

        // S -> Sb (C layout: col=lane&15, row=(lane>>4)*4+reg)
        #pragma unroll
        for (int jt = 0; jt < 4; ++jt) {
            #pragma unroll
            for (int i = 0; i < 4; ++i) {
                const int r = w * 16 + fq * 4 + i;
                const int c = jt * 16 + fr;
                Sb[(r * 64 + c) ^ ((r & 7) << 3)] = (ushort)f2bs(accS[jt][i]);
            }
        }
        __syncthreads();   // Sb visible; all At/Vt MFMA reads done -> U reusable

        // ================= Phase 2: out = base + S @ K =================
        const int jj = j0 + jr;
        const int g = (jj < n) ? mlist[jj] : -1;
        const float* bp = (cc == 0) ? (tok + tokbase) : (const float*)(out + tokbase);
        const f32x4 zf = {0.f, 0.f, 0.f, 0.f};

        f32x4 kreg[8];
        #pragma unroll
        for (int p = 0; p < 8; ++p)
            kreg[p] = (g >= 0)
                ? *(const f32x4*)(kbase + (size_t)g * ND + (q + 4 * p) * 4)
                : zf;

        for (int st = 0; st < 6; ++st) {
            if (st > 0) __syncthreads();   // prior strip's kT reads done
            #pragma unroll
            for (int p = 0; p < 8; ++p) {
                #pragma unroll
                for (int e = 0; e < 4; ++e) {
                    const int dc = (q + 4 * p) * 4 + e;
                    kT[(dc * 64 + jr) ^ ((dc & 7) << 3)] = (ushort)f2bs(kreg[p][e]);
                }
            }
            // residual loads (L2-hot: tok tile streamed in phase 1 / out just written)
            f32x4 acco[8];
            {
                const float* rbp = bp + (size_t)(w * 16 + fr) * ND + st * 128 + fq * 4;
                #pragma unroll
                for (int ct = 0; ct < 8; ++ct)
                    acco[ct] = *(const f32x4*)(rbp + ct * 16);
            }
            if (st < 5) {   // prefetch next strip's k rows
                const int c0 = (st + 1) * 128;
                #pragma unroll
                for (int p = 0; p < 8; ++p)
                    kreg[p] = (g >= 0)
                        ? *(const f32x4*)(kbase + (size_t)g * ND + c0 + (q + 4 * p) * 4)
                        : zf;
            }
            __syncthreads();   // kT visible

            const int srow = w * 16 + fr;          // B = S rows (l)
            const int ssw  = (srow & 7) << 3;
            #pragma unroll
            for (int ks = 0; ks < 2; ++ks) {
                bf16x8 bv = *(const bf16x8*)&Sb[(srow * 64 + ks * 32 + fq * 8) ^ ssw];
                #pragma unroll
                for (int ct = 0; ct < 8; ++ct) {
                    const int drow = ct * 16 + fr; // A = kT rows (dcol)
                    bf16x8 af = *(const bf16x8*)&kT[(drow * 64 + ks * 32 + fq * 8) ^ ((drow & 7) << 3)];
                    acco[ct] = __builtin_amdgcn_mfma_f32_16x16x32_bf16(af, bv, acco[ct], 0, 0, 0);
                }
            }
            float* ob = out + tokbase + (size_t)(w * 16 + fr) * ND + st * 128 + fq * 4;
            #pragma unroll
            for (int ct = 0; ct < 8; ++ct)
                *(f32x4*)(ob + ct * 16) = acco[ct];
        }
        __syncthreads();   // phase2 kT reads done before next chunk stages U
    }
}

extern "C" void kernel_launch(void* const* d_in, const int* in_sizes, int n_in,
                              void* d_out, int out_size, void* d_ws, size_t ws_size,
                              hipStream_t stream) {
    const int*   spk = (const int*)d_in[1];
    const float* tok = (const float*)d_in[2];
    const float* edu = (const float*)d_in[3];
    const float* Wk  = (const float*)d_in[4];
    const float* Wv  = (const float*)d_in[5];

    const size_t kv_floats = (size_t)NB * NT * ND;
    float* kws = (float*)d_ws;
    float* vws = kws + kv_floats;
    float* outp = (float*)d_out;

    projm_kernel<<<dim3(2048 / 64, ND / 64, 2), 256, 0, stream>>>(edu, Wk, Wv, kws, vws);
    fused_kernel<<<NB * NT, 256, 0, stream>>>(spk, tok, kws, vws, outp);
}